// Round 1
// baseline (149.597 us; speedup 1.0000x reference)
//
#include <hip/hip_runtime.h>

// ---------------------------------------------------------------------------
// CNN + FC + 2x GraphSAGE, collapsed.
//
// Since there is no nonlinearity between the two SAGE layers, the GNN part is
// linear in h (the 5-dim MLP output). Pushing the final 1-dim weights through
// both layers reduces everything to scalar per-(node,batch) fields:
//   a  = g2_wl @ g1_wl   (5)   r1 = g2_wr @ g1_wl (5)
//   c  = g2_wl @ g1_wr   (5)   r2 = g2_wr @ g1_wr (5)
//   kb1 = g2_wl . g1_bl        kb2 = g2_wr . g1_bl
//   s_a = a.h, s_r1 = r1.h, s_c = c.h, s_r2 = r2.h      (per node,batch)
//   u = meanAgg(s_a), v = meanAgg(s_r1)
//   out = meanAgg(u + s_c) + kb1*[deg>0] + g2_bl + v + kb2 + s_r2
// ---------------------------------------------------------------------------

__global__ void k_coefs(const float* __restrict__ g1_wl, const float* __restrict__ g1_bl,
                        const float* __restrict__ g1_wr, const float* __restrict__ g2_wl,
                        const float* __restrict__ g2_wr, float* __restrict__ coef) {
  if (blockIdx.x == 0 && threadIdx.x == 0) {
    for (int k = 0; k < 5; ++k) {
      float a = 0.f, r1 = 0.f, c = 0.f, r2 = 0.f;
      for (int j = 0; j < 20; ++j) {
        float wl = g1_wl[j * 5 + k], wr = g1_wr[j * 5 + k];
        a  += g2_wl[j] * wl;
        r1 += g2_wr[j] * wl;
        c  += g2_wl[j] * wr;
        r2 += g2_wr[j] * wr;
      }
      coef[k] = a; coef[5 + k] = r1; coef[10 + k] = c; coef[15 + k] = r2;
    }
    float kb1 = 0.f, kb2 = 0.f;
    for (int j = 0; j < 20; ++j) { kb1 += g2_wl[j] * g1_bl[j]; kb2 += g2_wr[j] * g1_bl[j]; }
    coef[20] = kb1; coef[21] = kb2;
  }
}

__global__ void k_deg(const int* __restrict__ dst, int E, int* __restrict__ degi) {
  int e = blockIdx.x * blockDim.x + threadIdx.x;
  if (e < E) atomicAdd(&degi[dst[e]], 1);
}

__global__ void k_inv(const int* __restrict__ degi, float* __restrict__ invd, int N) {
  int n = blockIdx.x * blockDim.x + threadIdx.x;
  if (n < N) invd[n] = 1.0f / fmaxf((float)degi[n], 1.0f);
}

// One thread per (b,n) row, memory order rr = b*N + n; x row = 108 contiguous f32.
__global__ __launch_bounds__(256) void k_mlp(
    const float* __restrict__ x,
    const float* __restrict__ w_t, const float* __restrict__ b_t,
    const float* __restrict__ w_r, const float* __restrict__ b_r,
    const float* __restrict__ w_tp, const float* __restrict__ b_tp,
    const float* __restrict__ w_ssr, const float* __restrict__ b_ssr,
    const float* __restrict__ f1w, const float* __restrict__ f1b,
    const float* __restrict__ f2w, const float* __restrict__ f2b,
    const float* __restrict__ coef,
    float* __restrict__ F1, float* __restrict__ F2, int N, int rows) {
  int rr = blockIdx.x * 256 + threadIdx.x;
  if (rr >= rows) return;
  const float* xp = x + (size_t)rr * 108;

  float feat[32];
#pragma unroll
  for (int i = 0; i < 3; ++i) {
    float4 v = *reinterpret_cast<const float4*>(xp + 4 * i);
    feat[4 * i + 0] = v.x; feat[4 * i + 1] = v.y; feat[4 * i + 2] = v.z; feat[4 * i + 3] = v.w;
  }
  const float* cw[4] = {w_t, w_r, w_tp, w_ssr};
  const float* cb[4] = {b_t, b_r, b_tp, b_ssr};
#pragma unroll
  for (int br = 0; br < 4; ++br) {
    float win[24];
#pragma unroll
    for (int i = 0; i < 6; ++i) {
      float4 v = *reinterpret_cast<const float4*>(xp + 12 + br * 24 + 4 * i);
      win[4 * i + 0] = v.x; win[4 * i + 1] = v.y; win[4 * i + 2] = v.z; win[4 * i + 3] = v.w;
    }
#pragma unroll
    for (int o = 0; o < 5; ++o) {
      float acc = cb[br][o];
#pragma unroll
      for (int k = 0; k < 24; ++k) acc = fmaf(win[k], cw[br][o * 24 + k], acc);
      feat[12 + br * 5 + o] = fmaxf(acc, 0.f);
    }
  }
  float h20[20];
#pragma unroll
  for (int o = 0; o < 20; ++o) {
    float acc = f1b[o];
#pragma unroll
    for (int i = 0; i < 32; ++i) acc = fmaf(feat[i], f1w[o * 32 + i], acc);
    h20[o] = fmaxf(acc, 0.f);
  }
  float h5[5];
#pragma unroll
  for (int o = 0; o < 5; ++o) {
    float acc = f2b[o];
#pragma unroll
    for (int i = 0; i < 20; ++i) acc = fmaf(h20[i], f2w[o * 20 + i], acc);
    h5[o] = acc;
  }
  float sa = 0.f, sr1 = 0.f, sc = 0.f, sr2 = 0.f;
#pragma unroll
  for (int k = 0; k < 5; ++k) {
    sa  = fmaf(h5[k], coef[k],      sa);
    sr1 = fmaf(h5[k], coef[5 + k],  sr1);
    sc  = fmaf(h5[k], coef[10 + k], sc);
    sr2 = fmaf(h5[k], coef[15 + k], sr2);
  }
  int b = rr / N;
  int n = rr - b * N;
  reinterpret_cast<float2*>(F1)[n * 16 + b] = make_float2(sa, sr1);
  reinterpret_cast<float2*>(F2)[n * 16 + b] = make_float2(sc, sr2);
}

// 32 threads per edge: j indexes [b][2] flat (16 batches x {s_a,s_r1}).
__global__ void k_agg1(const int* __restrict__ src, const int* __restrict__ dst, int E,
                       const float* __restrict__ F1, float* __restrict__ A1) {
  int t = blockIdx.x * blockDim.x + threadIdx.x;
  int e = t >> 5, j = t & 31;
  if (e < E) {
    int s = src[e], d = dst[e];
    atomicAdd(&A1[d * 32 + j], F1[s * 32 + j]);
  }
}

// W[n*16+b] = u + s_c  (u = mean-aggregated s_a)
__global__ void k_fin1(const float* __restrict__ A1, const float* __restrict__ F2,
                       const float* __restrict__ invd, float* __restrict__ W, int N) {
  int t = blockIdx.x * blockDim.x + threadIdx.x;
  if (t < N * 16) {
    int n = t >> 4, b = t & 15;
    W[t] = A1[n * 32 + 2 * b] * invd[n] + F2[n * 32 + 2 * b];
  }
}

// 16 threads per edge: scalar field W.
__global__ void k_agg2(const int* __restrict__ src, const int* __restrict__ dst, int E,
                       const float* __restrict__ W, float* __restrict__ A2) {
  int t = blockIdx.x * blockDim.x + threadIdx.x;
  int e = t >> 4, b = t & 15;
  if (e < E) {
    int s = src[e], d = dst[e];
    atomicAdd(&A2[d * 16 + b], W[s * 16 + b]);
  }
}

// out[b*N+n] = inv*(A2 + v_sum) + s_r2 + kb1*chi + kb2 + bl2
__global__ void k_final(const float* __restrict__ A1, const float* __restrict__ F2,
                        const float* __restrict__ A2, const float* __restrict__ invd,
                        const int* __restrict__ degi, const float* __restrict__ coef,
                        const float* __restrict__ g2_bl, float* __restrict__ out, int N) {
  int t = blockIdx.x * blockDim.x + threadIdx.x;
  if (t < 16 * N) {
    int b = t / N, n = t - b * N;
    float inv = invd[n];
    float chi = degi[n] > 0 ? 1.f : 0.f;
    float kb1 = coef[20], kb2 = coef[21], bl2 = g2_bl[0];
    out[t] = (A2[n * 16 + b] + A1[n * 32 + 2 * b + 1]) * inv
             + F2[n * 32 + 2 * b + 1] + kb1 * chi + kb2 + bl2;
  }
}

extern "C" void kernel_launch(void* const* d_in, const int* in_sizes, int n_in,
                              void* d_out, int out_size, void* d_ws, size_t ws_size,
                              hipStream_t stream) {
  const float* x     = (const float*)d_in[0];
  const int*   ei    = (const int*)d_in[1];
  const float* w_t   = (const float*)d_in[2];
  const float* b_t   = (const float*)d_in[3];
  const float* w_r   = (const float*)d_in[4];
  const float* b_r   = (const float*)d_in[5];
  const float* w_tp  = (const float*)d_in[6];
  const float* b_tp  = (const float*)d_in[7];
  const float* w_ssr = (const float*)d_in[8];
  const float* b_ssr = (const float*)d_in[9];
  const float* f1w   = (const float*)d_in[10];
  const float* f1b   = (const float*)d_in[11];
  const float* f2w   = (const float*)d_in[12];
  const float* f2b   = (const float*)d_in[13];
  const float* g1_wl = (const float*)d_in[14];
  const float* g1_bl = (const float*)d_in[15];
  const float* g1_wr = (const float*)d_in[16];
  const float* g2_wl = (const float*)d_in[17];
  const float* g2_bl = (const float*)d_in[18];
  const float* g2_wr = (const float*)d_in[19];
  float* out = (float*)d_out;

  const int E = in_sizes[1] / 2;
  const int N = out_size / 16;   // B = 16
  const int rows = out_size;     // N * B
  const int* src = ei;
  const int* dst = ei + E;

  // workspace layout (floats)
  float* ws   = (float*)d_ws;
  float* coef = ws;                       // 32
  int*   degi = (int*)(ws + 32);          // N
  float* invd = ws + 32 + N;              // N
  float* F1   = invd + N;                 // 32*N  [n][b][{s_a,s_r1}]
  float* F2   = F1 + (size_t)32 * N;      // 32*N  [n][b][{s_c,s_r2}]
  float* A1   = F2 + (size_t)32 * N;      // 32*N  accumulators
  float* A2   = A1 + (size_t)32 * N;      // 16*N
  float* W    = A2 + (size_t)16 * N;      // 16*N

  hipMemsetAsync(degi, 0, (size_t)N * sizeof(int), stream);
  hipMemsetAsync(A1, 0, (size_t)N * 32 * sizeof(float), stream);
  hipMemsetAsync(A2, 0, (size_t)N * 16 * sizeof(float), stream);

  k_coefs<<<1, 64, 0, stream>>>(g1_wl, g1_bl, g1_wr, g2_wl, g2_wr, coef);
  k_deg<<<(E + 255) / 256, 256, 0, stream>>>(dst, E, degi);
  k_inv<<<(N + 255) / 256, 256, 0, stream>>>(degi, invd, N);
  k_mlp<<<(rows + 255) / 256, 256, 0, stream>>>(
      x, w_t, b_t, w_r, b_r, w_tp, b_tp, w_ssr, b_ssr,
      f1w, f1b, f2w, f2b, coef, F1, F2, N, rows);
  {
    long long t1 = (long long)E * 32;
    k_agg1<<<(int)((t1 + 255) / 256), 256, 0, stream>>>(src, dst, E, F1, A1);
  }
  k_fin1<<<(N * 16 + 255) / 256, 256, 0, stream>>>(A1, F2, invd, W, N);
  {
    long long t2 = (long long)E * 16;
    k_agg2<<<(int)((t2 + 255) / 256), 256, 0, stream>>>(src, dst, E, W, A2);
  }
  k_final<<<(16 * N + 255) / 256, 256, 0, stream>>>(A1, F2, A2, invd, degi, coef, g2_bl, out, N);
}